// Round 18
// baseline (213.575 us; speedup 1.0000x reference)
//
#include <hip/hip_runtime.h>
#include <hip/hip_bf16.h>
#include <math.h>

// RegionalGNN: B=8192, NC=8, H=256, HD=1024, L=3.
// R18: k_net restructured around a continuous 96-chunk weight ring with counted
//      vmcnt (T3/T4): chunk = 8KB (one (kk,h) of 8 nj-panels, contiguous in the
//      frag-packed layout) staged by ONE global_load_lds per thread; 4-slot ring,
//      prefetch distance 3, per-phase {vmcnt(2); barrier; stage(n+3); 8 MFMA}.
//      No vmcnt(0) drains in-stream; prefetch flows through softmax/PV/epilogue
//      and across layers. LDS diet: ring 32KB + tst 4KB/wave (bf16 exchange) +
//      all-layer tables preloaded = 81408B -> 2 blocks/CU (R17 had 144KB -> 1).

typedef short bf16x8 __attribute__((ext_vector_type(8)));
typedef float f32x4  __attribute__((ext_vector_type(4)));

__device__ __forceinline__ float bflo(unsigned int u){ return __uint_as_float(u << 16); }
__device__ __forceinline__ float bfhi(unsigned int u){ return __uint_as_float(u & 0xffff0000u); }
__device__ __forceinline__ float bfs(short s){ return __uint_as_float((unsigned int)(unsigned short)s << 16); }
__device__ __forceinline__ unsigned short f2bf(float f){
  __hip_bfloat16 h = __float2bfloat16(f);
  return *reinterpret_cast<unsigned short*>(&h);
}
__device__ __forceinline__ int gsw(int r, int q){ return (r + 16*q) ^ (r >> 2); }
__device__ __forceinline__ void unpack8(uint4 a, float* o){
  o[0]=bflo(a.x); o[1]=bfhi(a.x); o[2]=bflo(a.y); o[3]=bfhi(a.y);
  o[4]=bflo(a.z); o[5]=bfhi(a.z); o[6]=bflo(a.w); o[7]=bfhi(a.w);
}
__device__ __forceinline__ uint4 pack8(const float* v){
  uint4 r;
  r.x = (unsigned int)f2bf(v[0]) | ((unsigned int)f2bf(v[1]) << 16);
  r.y = (unsigned int)f2bf(v[2]) | ((unsigned int)f2bf(v[3]) << 16);
  r.z = (unsigned int)f2bf(v[4]) | ((unsigned int)f2bf(v[5]) << 16);
  r.w = (unsigned int)f2bf(v[6]) | ((unsigned int)f2bf(v[7]) << 16);
  return r;
}
__device__ __forceinline__ void gload16(const void* g, void* l){
  __builtin_amdgcn_global_load_lds(
      (const __attribute__((address_space(1))) unsigned int*)g,
      (__attribute__((address_space(3))) unsigned int*)l, 16, 0, 0);
}
__device__ __forceinline__ bf16x8 shfl8(bf16x8 v, int src){
  union U { bf16x8 h; int u[4]; };
  U a, r; a.h = v;
  #pragma unroll
  for (int j = 0; j < 4; j++) r.u[j] = __shfl(a.u[j], src);
  return r.h;
}
__device__ __forceinline__ bf16x8 pk8(const float* v){
  bf16x8 r;
  #pragma unroll
  for (int j = 0; j < 8; j++) r[j] = (short)f2bf(v[j]);
  return r;
}
// frag-pack index for row-major [N][K] source element (n,k):
__device__ __forceinline__ int pidx(int n, int k){
  return (k >> 5)*8192 + (n >> 4)*512 + ((k >> 3) & 3)*128 + (n & 15)*8 + (k & 7);
}

// ---------------- prep1: convert (Wq,Wk,Wv) + transpose (Wi->packed, Wo x3, Wp->packed) ----------------
struct P1P {
  const float* csrc[3]; short* cdst[3];
  const float* tsrc[5]; short* tdst[5];
  int trows[5]; int tcols[5]; int tpack[5]; int toff[6];
};
__global__ __launch_bounds__(256) void k_prep1(P1P p){
  __shared__ float tile[64][65];
  int bid = blockIdx.x;
  if (bid < 1152){
    int s = bid / 384, lb = bid % 384;
    size_t e = (size_t)lb * 2048 + (size_t)threadIdx.x * 8;
    const float* src = p.csrc[s] + e;
    float4 v0 = *(const float4*)src;
    float4 v1 = *(const float4*)(src + 4);
    float v[8] = {v0.x,v0.y,v0.z,v0.w,v1.x,v1.y,v1.z,v1.w};
    *(uint4*)(p.cdst[s] + e) = pack8(v);
    return;
  }
  int tb = bid - 1152, s = 0;
  while (tb >= p.toff[s+1]) s++;
  int ti = tb - p.toff[s];
  int cols = p.tcols[s], rows = p.trows[s];
  int ntc = cols >> 6;
  int r0 = (ti / ntc) * 64, c0 = (ti % ntc) * 64;
  const float* src = p.tsrc[s];
  int row = threadIdx.x >> 2, jb = (threadIdx.x & 3) * 16;
  #pragma unroll
  for (int j = 0; j < 16; j += 4){
    float4 v = *(const float4*)(src + (size_t)(r0 + row) * cols + c0 + jb + j);
    tile[row][jb+j] = v.x; tile[row][jb+j+1] = v.y; tile[row][jb+j+2] = v.z; tile[row][jb+j+3] = v.w;
  }
  __syncthreads();
  short* dst = p.tdst[s];
  float tmp[16];
  #pragma unroll
  for (int j = 0; j < 16; j++) tmp[j] = tile[jb + j][row];
  if (p.tpack[s]){
    int n = c0 + row;
    #pragma unroll
    for (int gq = 0; gq < 2; gq++){
      int k = r0 + jb + gq*8;
      *(uint4*)(dst + pidx(n, k)) = pack8(&tmp[gq*8]);
    }
  } else {
    #pragma unroll
    for (int j = 0; j < 16; j += 8)
      *(uint4*)(dst + (size_t)(c0 + row) * rows + r0 + jb + j) = pack8(&tmp[j]);
  }
}

// ---------------- prep2: 64x64-tile precompute GEMM (packed output) + ck/cvo dots ----------------
struct GD2 { const short* A; const short* Bt; short* Cp; float scale; };
struct P2P {
  GD2 d[6];
  const short* Wkb; const short* WoTb;
  const float* bq; const float* bv; const float* bo;
  float* ck; float* cvo;
};
__global__ __launch_bounds__(256) void k_prep2(P2P p){
  __shared__ alignas(16) short As[64*128];
  __shared__ alignas(16) short Bs[64*128];
  __shared__ float sv[1024];
  const int bid = blockIdx.x, tid = threadIdx.x;
  if (bid < 96){
    const int lane = tid & 63, w = tid >> 6;
    const int wm = w >> 1, wn = w & 1;
    const int z = bid >> 4, rem = bid & 15, bx = rem >> 2, by = rem & 3;
    GD2 g = p.d[z];
    const int K = 1024;
    f32x4 acc[2][2] = {};
    for (int k0 = 0; k0 < K; k0 += 128){
      #pragma unroll
      for (int kc = 0; kc < 4; kc++){
        int ro = w*16 + (lane & 15);
        int co = k0 + kc*32 + (lane >> 4)*8;
        gload16(g.A  + (size_t)(bx*64 + ro)*K + co, &As[(kc*4 + w)*512]);
        gload16(g.Bt + (size_t)(by*64 + ro)*K + co, &Bs[(kc*4 + w)*512]);
      }
      __syncthreads();
      #pragma unroll
      for (int kc = 0; kc < 4; kc++){
        bf16x8 av[2], bv[2];
        #pragma unroll
        for (int mi = 0; mi < 2; mi++)
          av[mi] = *(const bf16x8*)&As[((kc*4 + wm*2 + mi)*64 + lane)*8];
        #pragma unroll
        for (int nj = 0; nj < 2; nj++)
          bv[nj] = *(const bf16x8*)&Bs[((kc*4 + wn*2 + nj)*64 + lane)*8];
        #pragma unroll
        for (int mi = 0; mi < 2; mi++)
          #pragma unroll
          for (int nj = 0; nj < 2; nj++)
            acc[mi][nj] = __builtin_amdgcn_mfma_f32_16x16x32_bf16(av[mi], bv[nj], acc[mi][nj], 0, 0, 0);
      }
      __syncthreads();
    }
    #pragma unroll
    for (int mi = 0; mi < 2; mi++)
      #pragma unroll
      for (int nj = 0; nj < 2; nj++)
        #pragma unroll
        for (int j = 0; j < 4; j++){
          int r = bx*64 + wm*32 + mi*16 + (lane >> 4)*4 + j;
          int c = by*64 + wn*32 + nj*16 + (lane & 15);
          g.Cp[pidx(r, c)] = (short)f2bf(acc[mi][nj][j] * g.scale);
        }
    return;
  }
  int v = bid - 96;
  int job = v / 3, l = v % 3;
  const short* rows = (job == 0 ? p.Wkb : p.WoTb) + (size_t)l*262144;
  const float* vec  = (job == 0 ? p.bq : p.bv) + l*1024;
  const float scale = (job == 0) ? 0.0625f : 1.0f;
  for (int i = tid; i < 1024; i += 256) sv[i] = vec[i];
  __syncthreads();
  const int row = tid >> 3, sub = tid & 7;
  for (int pass = 0; pass < 8; pass++){
    int r = pass*32 + row;
    const short* rp = rows + (size_t)r*1024;
    float acc = 0.f;
    #pragma unroll
    for (int i = 0; i < 16; i++){
      int d = sub*8 + i*64;
      uint4 vv = *(const uint4*)(rp + d);
      float f[8]; unpack8(vv, f);
      #pragma unroll
      for (int j = 0; j < 8; j++) acc = fmaf(f[j], sv[d + j], acc);
    }
    acc += __shfl_xor(acc, 1); acc += __shfl_xor(acc, 2); acc += __shfl_xor(acc, 4);
    if (sub == 0){
      float o = acc * scale;
      if (job == 1) o += p.bo[l*256 + r];
      (job == 0 ? p.ck : p.cvo)[l*256 + r] = o;
    }
  }
}

// ---------------- mega-kernel (R18): chunked ring, counted vmcnt, 2 blocks/CU ----------------
__global__ __launch_bounds__(512, 2) void k_net(
    const float* __restrict__ rf, const short* __restrict__ WiT,
    const float* __restrict__ bi, const float* __restrict__ emb,
    const short* __restrict__ Wqk, const short* __restrict__ Wvo,
    const float* __restrict__ ckv, const float* __restrict__ cvov,
    const float* __restrict__ lng, const float* __restrict__ lnb,
    const short* __restrict__ WpT, const float* __restrict__ bpv,
    const float* __restrict__ lpg, const float* __restrict__ lpb,
    float* __restrict__ outp){
  const int tid = threadIdx.x, lane = tid & 63, w = tid >> 6;
  const int b0 = blockIdx.x * 16;
  const int dsub = (lane >> 4) * 8;
  const int glane = gsw(lane & 15, lane >> 4);
  // LDS: 32768 + 32768 + 8192 + 1536 + 3072 + 1536 + 1536 = 81408 B (2 blocks/CU)
  __shared__ alignas(16) short tst[8][2048];      // 32 KB: per-wave 4KB stash
  __shared__ alignas(16) short wbuf[4][4096];     // 32 KB: 4-slot chunk ring
  __shared__ alignas(16) float atn[8][16][16];    // 8 KB
  __shared__ short ckb3[768];                     // bf16 ck, all layers
  __shared__ float sadd3[768];                    // f32 cvo, all layers
  __shared__ short sg3[768];                      // bf16 LN gamma
  __shared__ short sb3[768];                      // bf16 LN beta

  #define LKW  asm volatile("s_waitcnt lgkmcnt(0)" ::: "memory")
  #define VMW0 asm volatile("s_waitcnt vmcnt(0)" ::: "memory")
  #define VMW1 asm volatile("s_waitcnt vmcnt(1)" ::: "memory")
  #define VMW2 asm volatile("s_waitcnt vmcnt(2)" ::: "memory")
  #define BAR  __builtin_amdgcn_s_barrier()

  // chunk n (0..95): layer n>>5, gemm (n>>4)&1, c = n&15 -> (h = c>>3, kk = c&7)
  auto STAGE = [&](int n){
    int cc = n & 15;
    const short* W = (((n >> 4) & 1) ? Wvo : Wqk) + (n >> 5)*65536;
    const short* src = W + ((((cc & 7)*16 + (cc >> 3)*8) << 9) + tid*8);
    gload16(src, &wbuf[n & 3][tid*8]);
  };

  // ===== input projection: h = rf@Wi + bi (B frag-packed direct-global) =====
  float* hst  = (float*)&tst[0][0];   // [16][264] f32 (26 KB inside tst)
  float* embs = hst + 16*264;
  float* bis  = embs + 2048;
  if (tid < 256) bis[tid] = bi[tid];
  for (int i = tid; i < 2048; i += 512) embs[i] = emb[i];
  f32x4 hacc[2] = {};
  #pragma unroll
  for (int kk = 0; kk < 16; kk++){
    const float* ap = rf + (size_t)(b0 + (lane & 15)) * 512 + kk*32 + dsub;
    float4 a0 = *(const float4*)ap, a1 = *(const float4*)(ap + 4);
    float af[8] = {a0.x,a0.y,a0.z,a0.w,a1.x,a1.y,a1.z,a1.w};
    bf16x8 av = pk8(af);
    #pragma unroll
    for (int nj = 0; nj < 2; nj++){
      bf16x8 bv = *(const bf16x8*)(WiT + (size_t)(kk*16 + w*2 + nj)*512 + lane*8);
      hacc[nj] = __builtin_amdgcn_mfma_f32_16x16x32_bf16(av, bv, hacc[nj], 0, 0, 0);
    }
  }
  // preload all-layer tables (before barrier so hst write below fences them too)
  for (int i = tid; i < 768; i += 512){
    ckb3[i]  = (short)f2bf(ckv[i]);
    sadd3[i] = cvov[i];
    sg3[i]   = (short)f2bf(lng[i]);
    sb3[i]   = (short)f2bf(lnb[i]);
  }
  __syncthreads();   // bis/embs published
  #pragma unroll
  for (int nj = 0; nj < 2; nj++)
    #pragma unroll
    for (int jj = 0; jj < 4; jj++){
      int m = (lane >> 4)*4 + jj, col = w*32 + nj*16 + (lane & 15);
      hst[m*264 + col] = hacc[nj][jj] + bis[col];
    }
  __syncthreads();   // hst published
  bf16x8 xf[8];
  {
    int r15 = lane & 15;
    int bt = w*2 + (r15 >> 3), ct = r15 & 7;
    #pragma unroll
    for (int c = 0; c < 8; c++){
      float v8[8];
      #pragma unroll
      for (int e = 0; e < 8; e++){
        int d = dsub + 32*c + e;
        v8[e] = hst[bt*264 + d] + embs[ct*256 + d];
      }
      xf[c] = pk8(v8);
    }
  }
  VMW0; __syncthreads();   // drain all VMEM (rf/WiT/tables) before the ring stream
  STAGE(0); STAGE(1); STAGE(2);

  const unsigned long long MASK64 = 0x02191D69752B857EULL;

  // ===== layers (chunk stream n = l*32 + g*16 + c, prefetch distance 3) =====
  #pragma unroll 1
  for (int l = 0; l < 3; ++l){
    const short* ckb  = ckb3  + l*256;
    const float* sadd = sadd3 + l*256;
    const short* sg   = sg3   + l*256;
    const short* sb   = sb3   + l*256;
    const bool lgl = (l == 2);   // last layer (tail lives in g==1)

    // ---- GEMM1: T = X @ Wqk ----
    f32x4 sacc = {0.f, 0.f, 0.f, 0.f};
    #pragma unroll
    for (int h = 0; h < 2; h++){
      f32x4 acc[8] = {};
      #pragma unroll
      for (int kk = 0; kk < 8; kk++){
        const int n = l*32 + h*8 + kk;
        VMW2; BAR;
        STAGE(n + 3);
        const short* P = &wbuf[n & 3][0];
        #pragma unroll
        for (int nj = 0; nj < 8; nj++){
          bf16x8 bv = *(const bf16x8*)&P[nj*512 + lane*8];
          acc[nj] = __builtin_amdgcn_mfma_f32_16x16x32_bf16(xf[kk], bv, acc[nj], 0, 0, 0);
        }
      }
      // T-half -> per-wave stash (bf16, swizzled), then score MFMA
      #pragma unroll
      for (int nj = 0; nj < 8; nj++)
        #pragma unroll
        for (int jj = 0; jj < 4; jj++){
          int i_ = (lane >> 4)*4 + jj, nl = nj*16 + (lane & 15);
          tst[w][(nl >> 5)*512 + gsw(i_, (nl >> 3) & 3)*8 + (nl & 7)] = (short)f2bf(acc[nj][jj]);
        }
      LKW; __builtin_amdgcn_sched_barrier(0);
      #pragma unroll
      for (int cl = 0; cl < 4; cl++){
        bf16x8 tf = *(const bf16x8*)&tst[w][cl*512 + glane*8];
        sacc = __builtin_amdgcn_mfma_f32_16x16x32_bf16(tf, xf[h*4 + cl], sacc, 0, 0, 0);
      }
      LKW;   // stash reads drained before next-half overwrite
    }

    // ---- skv[m] = X[m].ck ----
    float skv = 0.f;
    #pragma unroll
    for (int c = 0; c < 8; c++){
      bf16x8 cv = *(const bf16x8*)&ckb[c*32 + dsub];
      #pragma unroll
      for (int e = 0; e < 8; e++) skv = fmaf(bfs(xf[c][e]), bfs(cv[e]), skv);
    }
    skv += __shfl_xor(skv, 16); skv += __shfl_xor(skv, 32);

    // ---- softmax (C-layout) -> atn[w] ----
    #pragma unroll
    for (int jj = 0; jj < 4; jj++){
      int i_ = (lane >> 4)*4 + jj, j_ = lane & 15;
      bool ok = (((i_ ^ j_) & 8) == 0) &&
                ((MASK64 >> (((i_ & 7) << 3) | (j_ & 7))) & 1ull);
      float sv = ok ? (sacc[jj] + skv) : -3.0e38f;
      float mx = sv;
      mx = fmaxf(mx, __shfl_xor(mx, 1));
      mx = fmaxf(mx, __shfl_xor(mx, 2));
      mx = fmaxf(mx, __shfl_xor(mx, 4));
      float e = ok ? __expf(sv - mx) : 0.f;
      float sum = e;
      sum += __shfl_xor(sum, 1); sum += __shfl_xor(sum, 2); sum += __shfl_xor(sum, 4);
      atn[w][i_][j_] = e / sum;
    }
    LKW;

    // ---- PV: yfrag (A-layout) via shfl from xf ----
    bf16x8 yfrag[8];
    {
      float4 A0 = *(const float4*)&atn[w][lane & 15][lane & 8];
      float4 A1 = *(const float4*)&atn[w][lane & 15][(lane & 8) + 4];
      float am[8] = {A0.x, A0.y, A0.z, A0.w, A1.x, A1.y, A1.z, A1.w};
      #pragma unroll
      for (int c = 0; c < 8; c++){
        float a8[8] = {0,0,0,0,0,0,0,0};
        #pragma unroll
        for (int mi = 0; mi < 8; mi++){
          bf16x8 xs = shfl8(xf[c], (lane & 48) | (lane & 8) | mi);
          #pragma unroll
          for (int e = 0; e < 8; e++) a8[e] = fmaf(am[mi], bfs(xs[e]), a8[e]);
        }
        yfrag[c] = pk8(a8);
      }
    }

    // ---- GEMM2: out = y @ Wvo; bf16 exchange epilogue per half ----
    float rs = 0.f, rq = 0.f;
    #pragma unroll
    for (int h = 0; h < 2; h++){
      f32x4 acc[8] = {};
      #pragma unroll
      for (int kk = 0; kk < 8; kk++){
        const int c = h*8 + kk;
        const int n = l*32 + 16 + c;
        if (lgl && c == 14){ VMW1; } else if (lgl && c == 15){ VMW0; } else { VMW2; }
        BAR;
        if (!(lgl && c >= 13)) STAGE(n + 3);
        const short* P = &wbuf[n & 3][0];
        #pragma unroll
        for (int nj = 0; nj < 8; nj++){
          bf16x8 bv = *(const bf16x8*)&P[nj*512 + lane*8];
          acc[nj] = __builtin_amdgcn_mfma_f32_16x16x32_bf16(yfrag[kk], bv, acc[nj], 0, 0, 0);
        }
      }
      // scatter bf16(acc) into per-wave stash (A-frag addressing over local col)
      #pragma unroll
      for (int nj = 0; nj < 8; nj++)
        #pragma unroll
        for (int jj = 0; jj < 4; jj++){
          int i_ = (lane >> 4)*4 + jj;
          int dq = nj*16 + (lane & 15);
          tst[w][(dq >> 5)*512 + gsw(i_, (dq >> 3) & 3)*8 + (dq & 7)] = (short)f2bf(acc[nj][jj]);
        }
      LKW; __builtin_amdgcn_sched_barrier(0);
      // read back contiguous; t = acc + cvo + residual(xf); stats; xf <- bf16(t)
      #pragma unroll
      for (int lc = 0; lc < 4; lc++){
        int c = h*4 + lc;
        float v8[8];
        #pragma unroll
        for (int e = 0; e < 8; e++){
          int d = 32*c + dsub + e;
          float t = bfs(tst[w][lc*512 + glane*8 + e]) + sadd[d] + bfs(xf[c][e]);
          rs += t; rq = fmaf(t, t, rq);
          v8[e] = t;
        }
        xf[c] = pk8(v8);
      }
      LKW;   // reads drained before h1 overwrites stash (and before next layer)
    }
    // ---- per-row LN stats + apply ----
    rs += __shfl_xor(rs, 16); rs += __shfl_xor(rs, 32);
    rq += __shfl_xor(rq, 16); rq += __shfl_xor(rq, 32);
    float mn = rs * (1.f/256.f);
    float var = rq * (1.f/256.f) - mn*mn;
    float rr = rsqrtf(fmaxf(var, 0.f) + 1e-5f);
    #pragma unroll
    for (int c = 0; c < 8; c++){
      float v8[8];
      #pragma unroll
      for (int e = 0; e < 8; e++){
        int d = 32*c + dsub + e;
        v8[e] = (bfs(xf[c][e]) - mn) * rr * bfs(sg[d]) + bfs(sb[d]);
      }
      xf[c] = pk8(v8);
    }
  } // layers

  // ===== head: GDP-reduce -> Astage -> GEMM vs frag-packed WpT -> LN -> GELU =====
  __syncthreads();   // tst becomes cross-wave Astage
  short* Ast = &tst[0][0];   // [16][264] bf16 (8.4 KB)
  {
    int c7 = lane & 7;
    float g = (c7 == 0) ? 0.4f : (c7 == 1) ? 0.15f : (c7 == 2) ? 0.12f :
              (c7 == 3) ? 0.1f : (c7 == 4) ? 0.08f : (c7 == 5) ? 0.08f :
              (c7 == 6) ? 0.05f : 0.02f;
    #pragma unroll
    for (int c = 0; c < 8; c++){
      float v8[8];
      #pragma unroll
      for (int e = 0; e < 8; e++){
        float v = g * bfs(xf[c][e]);
        v += __shfl_xor(v, 1); v += __shfl_xor(v, 2); v += __shfl_xor(v, 4);
        v8[e] = v;
      }
      if ((lane & 7) == 0){
        int bt = w*2 + ((lane >> 3) & 1);
        *(bf16x8*)&Ast[bt*264 + dsub + 32*c] = pk8(v8);
      }
    }
  }
  __syncthreads();
  float* redS  = &atn[0][0][0];          // aliases (atn dead)
  float* redQ  = redS + 128;
  float* s_mn  = redQ + 128;
  float* s_rs  = s_mn + 16;
  f32x4 ha[2] = {};
  #pragma unroll
  for (int kk = 0; kk < 8; kk++){
    bf16x8 av = *(const bf16x8*)&Ast[(lane & 15)*264 + kk*32 + dsub];
    #pragma unroll
    for (int nj = 0; nj < 2; nj++){
      bf16x8 bv = *(const bf16x8*)(WpT + (size_t)(kk*16 + w*2 + nj)*512 + lane*8);
      ha[nj] = __builtin_amdgcn_mfma_f32_16x16x32_bf16(av, bv, ha[nj], 0, 0, 0);
    }
  }
  #pragma unroll
  for (int jj = 0; jj < 4; jj++){
    float s = 0.f, q = 0.f;
    #pragma unroll
    for (int nj = 0; nj < 2; nj++){
      int cx = w*32 + nj*16 + (lane & 15);
      float t = ha[nj][jj] + bpv[cx];
      ha[nj][jj] = t;
      s += t; q = fmaf(t, t, q);
    }
    s += __shfl_xor(s, 1); q += __shfl_xor(q, 1);
    s += __shfl_xor(s, 2); q += __shfl_xor(q, 2);
    s += __shfl_xor(s, 4); q += __shfl_xor(q, 4);
    s += __shfl_xor(s, 8); q += __shfl_xor(q, 8);
    if ((lane & 15) == 0){
      int rl = (lane >> 4)*4 + jj;
      redS[w*16 + rl] = s; redQ[w*16 + rl] = q;
    }
  }
  __syncthreads();
  if (tid < 16){
    float sm = 0.f, sq = 0.f;
    #pragma unroll
    for (int w2 = 0; w2 < 8; w2++){ sm += redS[w2*16 + tid]; sq += redQ[w2*16 + tid]; }
    float mn = sm * (1.f/256.f);
    float var = sq * (1.f/256.f) - mn*mn;
    s_mn[tid] = mn;
    s_rs[tid] = rsqrtf(fmaxf(var, 0.f) + 1e-5f);
  }
  __syncthreads();
  #pragma unroll
  for (int jj = 0; jj < 4; jj++){
    int rl = (lane >> 4)*4 + jj;
    float mn = s_mn[rl], rstd = s_rs[rl];
    #pragma unroll
    for (int nj = 0; nj < 2; nj++){
      int cx = w*32 + nj*16 + (lane & 15);
      float y = (ha[nj][jj] - mn) * rstd * lpg[cx] + lpb[cx];
      outp[(size_t)(b0 + rl)*256 + cx] = 0.5f * y * (1.0f + erff(y * 0.70710678118654752f));
    }
  }
  #undef LKW
  #undef VMW0
  #undef VMW1
  #undef VMW2
  #undef BAR
}

extern "C" void kernel_launch(void* const* d_in, const int* in_sizes, int n_in,
                              void* d_out, int out_size, void* d_ws, size_t ws_size,
                              hipStream_t stream){
  (void)in_sizes; (void)n_in; (void)out_size; (void)ws_size;
  const float* rf  = (const float*)d_in[0];
  const float* Wi  = (const float*)d_in[1];
  const float* bi  = (const float*)d_in[2];
  const float* emb = (const float*)d_in[3];
  const float* Wq  = (const float*)d_in[4];
  const float* bq  = (const float*)d_in[5];
  const float* Wk  = (const float*)d_in[6];
  const float* bk  = (const float*)d_in[7];
  const float* Wv  = (const float*)d_in[8];
  const float* bv  = (const float*)d_in[9];
  const float* Wo  = (const float*)d_in[10];
  const float* bo  = (const float*)d_in[11];
  const float* lng = (const float*)d_in[12];
  const float* lnb = (const float*)d_in[13];
  const float* Wp  = (const float*)d_in[14];
  const float* bp  = (const float*)d_in[15];
  const float* lpg = (const float*)d_in[16];
  const float* lpb = (const float*)d_in[17];
  (void)bk;

  char* ws = (char*)d_ws;
  short* Wqb  = (short*)(ws);                      // [3][256][1024] bf16
  short* Wkb  = (short*)(ws + 1572864ull);
  short* Wvb  = (short*)(ws + 3145728ull);
  short* WoTb = (short*)(ws + 4718592ull);         // [3][256][1024] row-major
  short* WqkP = (short*)(ws + 6291456ull);         // [3][8][16][512] packed (scaled 1/16)
  short* WvoP = (short*)(ws + 6684672ull);         // [3][8][16][512] packed
  short* WiTP = (short*)(ws + 7077888ull);         // [16][16][512] packed
  short* WpTP = (short*)(ws + 7340032ull);         // [8][16][512] packed
  float* ckv  = (float*)(ws + 7471104ull);
  float* cvov = (float*)(ws + 7474176ull);

  { P1P p;
    p.csrc[0]=Wq; p.cdst[0]=Wqb;
    p.csrc[1]=Wk; p.cdst[1]=Wkb;
    p.csrc[2]=Wv; p.cdst[2]=Wvb;
    p.tsrc[0]=Wi;        p.tdst[0]=WiTP;          p.trows[0]=512;  p.tcols[0]=256; p.tpack[0]=1;
    p.tsrc[1]=Wo;        p.tdst[1]=WoTb;          p.trows[1]=1024; p.tcols[1]=256; p.tpack[1]=0;
    p.tsrc[2]=Wo+262144; p.tdst[2]=WoTb+262144;   p.trows[2]=1024; p.tcols[2]=256; p.tpack[2]=0;
    p.tsrc[3]=Wo+524288; p.tdst[3]=WoTb+524288;   p.trows[3]=1024; p.tcols[3]=256; p.tpack[3]=0;
    p.tsrc[4]=Wp;        p.tdst[4]=WpTP;          p.trows[4]=256;  p.tcols[4]=256; p.tpack[4]=1;
    p.toff[0]=0; p.toff[1]=32; p.toff[2]=96; p.toff[3]=160; p.toff[4]=224; p.toff[5]=240;
    k_prep1<<<dim3(1392), dim3(256), 0, stream>>>(p); }

  { P2P p;
    for (int l = 0; l < 3; l++){
      p.d[l]   = GD2{ Wkb  + l*262144, Wqb + l*262144, WqkP + l*65536, 0.0625f };
      p.d[3+l] = GD2{ WoTb + l*262144, Wvb + l*262144, WvoP + l*65536, 1.0f };
    }
    p.Wkb = Wkb; p.WoTb = WoTb;
    p.bq = bq; p.bv = bv; p.bo = bo;
    p.ck = ckv; p.cvo = cvov;
    k_prep2<<<dim3(102), dim3(256), 0, stream>>>(p); }

  k_net<<<dim3(512), dim3(512), 0, stream>>>(rf, WiTP, bi, emb, WqkP, WvoP,
      ckv, cvov, lng, lnb, WpTP, bp, lpg, lpb, (float*)d_out);
}

// Round 19
// 212.744 us; speedup vs baseline: 1.0039x; 1.0039x over previous
//
#include <hip/hip_runtime.h>
#include <hip/hip_bf16.h>
#include <math.h>

// RegionalGNN: B=8192, NC=8, H=256, HD=1024, L=3.
// R19: LDS diet to force TRUE 2 blocks/CU. R18 declared 81408B; 2x=162816 fits the
//      163840 limit by only 1KB and occupancy stayed 23% (1 block/CU) -> the 2nd
//      block never co-resided. Delete the dedicated 8KB atn buffer: alias atn[w]
//      into tst[w] (dead from post-score LKW until GEMM2 exchange; same-wave LDS
//      ops are in-order). Head scratch -> dead tst[6]. LDS 73216B (2x = 146432,
//      17KB margin). Everything else identical to R18.

typedef short bf16x8 __attribute__((ext_vector_type(8)));
typedef float f32x4  __attribute__((ext_vector_type(4)));

__device__ __forceinline__ float bflo(unsigned int u){ return __uint_as_float(u << 16); }
__device__ __forceinline__ float bfhi(unsigned int u){ return __uint_as_float(u & 0xffff0000u); }
__device__ __forceinline__ float bfs(short s){ return __uint_as_float((unsigned int)(unsigned short)s << 16); }
__device__ __forceinline__ unsigned short f2bf(float f){
  __hip_bfloat16 h = __float2bfloat16(f);
  return *reinterpret_cast<unsigned short*>(&h);
}
__device__ __forceinline__ int gsw(int r, int q){ return (r + 16*q) ^ (r >> 2); }
__device__ __forceinline__ void unpack8(uint4 a, float* o){
  o[0]=bflo(a.x); o[1]=bfhi(a.x); o[2]=bflo(a.y); o[3]=bfhi(a.y);
  o[4]=bflo(a.z); o[5]=bfhi(a.z); o[6]=bflo(a.w); o[7]=bfhi(a.w);
}
__device__ __forceinline__ uint4 pack8(const float* v){
  uint4 r;
  r.x = (unsigned int)f2bf(v[0]) | ((unsigned int)f2bf(v[1]) << 16);
  r.y = (unsigned int)f2bf(v[2]) | ((unsigned int)f2bf(v[3]) << 16);
  r.z = (unsigned int)f2bf(v[4]) | ((unsigned int)f2bf(v[5]) << 16);
  r.w = (unsigned int)f2bf(v[6]) | ((unsigned int)f2bf(v[7]) << 16);
  return r;
}
__device__ __forceinline__ void gload16(const void* g, void* l){
  __builtin_amdgcn_global_load_lds(
      (const __attribute__((address_space(1))) unsigned int*)g,
      (__attribute__((address_space(3))) unsigned int*)l, 16, 0, 0);
}
__device__ __forceinline__ bf16x8 shfl8(bf16x8 v, int src){
  union U { bf16x8 h; int u[4]; };
  U a, r; a.h = v;
  #pragma unroll
  for (int j = 0; j < 4; j++) r.u[j] = __shfl(a.u[j], src);
  return r.h;
}
__device__ __forceinline__ bf16x8 pk8(const float* v){
  bf16x8 r;
  #pragma unroll
  for (int j = 0; j < 8; j++) r[j] = (short)f2bf(v[j]);
  return r;
}
// frag-pack index for row-major [N][K] source element (n,k):
__device__ __forceinline__ int pidx(int n, int k){
  return (k >> 5)*8192 + (n >> 4)*512 + ((k >> 3) & 3)*128 + (n & 15)*8 + (k & 7);
}

// ---------------- prep1: convert (Wq,Wk,Wv) + transpose (Wi->packed, Wo x3, Wp->packed) ----------------
struct P1P {
  const float* csrc[3]; short* cdst[3];
  const float* tsrc[5]; short* tdst[5];
  int trows[5]; int tcols[5]; int tpack[5]; int toff[6];
};
__global__ __launch_bounds__(256) void k_prep1(P1P p){
  __shared__ float tile[64][65];
  int bid = blockIdx.x;
  if (bid < 1152){
    int s = bid / 384, lb = bid % 384;
    size_t e = (size_t)lb * 2048 + (size_t)threadIdx.x * 8;
    const float* src = p.csrc[s] + e;
    float4 v0 = *(const float4*)src;
    float4 v1 = *(const float4*)(src + 4);
    float v[8] = {v0.x,v0.y,v0.z,v0.w,v1.x,v1.y,v1.z,v1.w};
    *(uint4*)(p.cdst[s] + e) = pack8(v);
    return;
  }
  int tb = bid - 1152, s = 0;
  while (tb >= p.toff[s+1]) s++;
  int ti = tb - p.toff[s];
  int cols = p.tcols[s], rows = p.trows[s];
  int ntc = cols >> 6;
  int r0 = (ti / ntc) * 64, c0 = (ti % ntc) * 64;
  const float* src = p.tsrc[s];
  int row = threadIdx.x >> 2, jb = (threadIdx.x & 3) * 16;
  #pragma unroll
  for (int j = 0; j < 16; j += 4){
    float4 v = *(const float4*)(src + (size_t)(r0 + row) * cols + c0 + jb + j);
    tile[row][jb+j] = v.x; tile[row][jb+j+1] = v.y; tile[row][jb+j+2] = v.z; tile[row][jb+j+3] = v.w;
  }
  __syncthreads();
  short* dst = p.tdst[s];
  float tmp[16];
  #pragma unroll
  for (int j = 0; j < 16; j++) tmp[j] = tile[jb + j][row];
  if (p.tpack[s]){
    int n = c0 + row;
    #pragma unroll
    for (int gq = 0; gq < 2; gq++){
      int k = r0 + jb + gq*8;
      *(uint4*)(dst + pidx(n, k)) = pack8(&tmp[gq*8]);
    }
  } else {
    #pragma unroll
    for (int j = 0; j < 16; j += 8)
      *(uint4*)(dst + (size_t)(c0 + row) * rows + r0 + jb + j) = pack8(&tmp[j]);
  }
}

// ---------------- prep2: 64x64-tile precompute GEMM (packed output) + ck/cvo dots ----------------
struct GD2 { const short* A; const short* Bt; short* Cp; float scale; };
struct P2P {
  GD2 d[6];
  const short* Wkb; const short* WoTb;
  const float* bq; const float* bv; const float* bo;
  float* ck; float* cvo;
};
__global__ __launch_bounds__(256) void k_prep2(P2P p){
  __shared__ alignas(16) short As[64*128];
  __shared__ alignas(16) short Bs[64*128];
  __shared__ float sv[1024];
  const int bid = blockIdx.x, tid = threadIdx.x;
  if (bid < 96){
    const int lane = tid & 63, w = tid >> 6;
    const int wm = w >> 1, wn = w & 1;
    const int z = bid >> 4, rem = bid & 15, bx = rem >> 2, by = rem & 3;
    GD2 g = p.d[z];
    const int K = 1024;
    f32x4 acc[2][2] = {};
    for (int k0 = 0; k0 < K; k0 += 128){
      #pragma unroll
      for (int kc = 0; kc < 4; kc++){
        int ro = w*16 + (lane & 15);
        int co = k0 + kc*32 + (lane >> 4)*8;
        gload16(g.A  + (size_t)(bx*64 + ro)*K + co, &As[(kc*4 + w)*512]);
        gload16(g.Bt + (size_t)(by*64 + ro)*K + co, &Bs[(kc*4 + w)*512]);
      }
      __syncthreads();
      #pragma unroll
      for (int kc = 0; kc < 4; kc++){
        bf16x8 av[2], bv[2];
        #pragma unroll
        for (int mi = 0; mi < 2; mi++)
          av[mi] = *(const bf16x8*)&As[((kc*4 + wm*2 + mi)*64 + lane)*8];
        #pragma unroll
        for (int nj = 0; nj < 2; nj++)
          bv[nj] = *(const bf16x8*)&Bs[((kc*4 + wn*2 + nj)*64 + lane)*8];
        #pragma unroll
        for (int mi = 0; mi < 2; mi++)
          #pragma unroll
          for (int nj = 0; nj < 2; nj++)
            acc[mi][nj] = __builtin_amdgcn_mfma_f32_16x16x32_bf16(av[mi], bv[nj], acc[mi][nj], 0, 0, 0);
      }
      __syncthreads();
    }
    #pragma unroll
    for (int mi = 0; mi < 2; mi++)
      #pragma unroll
      for (int nj = 0; nj < 2; nj++)
        #pragma unroll
        for (int j = 0; j < 4; j++){
          int r = bx*64 + wm*32 + mi*16 + (lane >> 4)*4 + j;
          int c = by*64 + wn*32 + nj*16 + (lane & 15);
          g.Cp[pidx(r, c)] = (short)f2bf(acc[mi][nj][j] * g.scale);
        }
    return;
  }
  int v = bid - 96;
  int job = v / 3, l = v % 3;
  const short* rows = (job == 0 ? p.Wkb : p.WoTb) + (size_t)l*262144;
  const float* vec  = (job == 0 ? p.bq : p.bv) + l*1024;
  const float scale = (job == 0) ? 0.0625f : 1.0f;
  for (int i = tid; i < 1024; i += 256) sv[i] = vec[i];
  __syncthreads();
  const int row = tid >> 3, sub = tid & 7;
  for (int pass = 0; pass < 8; pass++){
    int r = pass*32 + row;
    const short* rp = rows + (size_t)r*1024;
    float acc = 0.f;
    #pragma unroll
    for (int i = 0; i < 16; i++){
      int d = sub*8 + i*64;
      uint4 vv = *(const uint4*)(rp + d);
      float f[8]; unpack8(vv, f);
      #pragma unroll
      for (int j = 0; j < 8; j++) acc = fmaf(f[j], sv[d + j], acc);
    }
    acc += __shfl_xor(acc, 1); acc += __shfl_xor(acc, 2); acc += __shfl_xor(acc, 4);
    if (sub == 0){
      float o = acc * scale;
      if (job == 1) o += p.bo[l*256 + r];
      (job == 0 ? p.ck : p.cvo)[l*256 + r] = o;
    }
  }
}

// ---------------- mega-kernel (R19): 73216B LDS -> true 2 blocks/CU ----------------
__global__ __launch_bounds__(512, 2) void k_net(
    const float* __restrict__ rf, const short* __restrict__ WiT,
    const float* __restrict__ bi, const float* __restrict__ emb,
    const short* __restrict__ Wqk, const short* __restrict__ Wvo,
    const float* __restrict__ ckv, const float* __restrict__ cvov,
    const float* __restrict__ lng, const float* __restrict__ lnb,
    const short* __restrict__ WpT, const float* __restrict__ bpv,
    const float* __restrict__ lpg, const float* __restrict__ lpb,
    float* __restrict__ outp){
  const int tid = threadIdx.x, lane = tid & 63, w = tid >> 6;
  const int b0 = blockIdx.x * 16;
  const int dsub = (lane >> 4) * 8;
  const int glane = gsw(lane & 15, lane >> 4);
  // LDS: 32768 + 32768 + 1536 + 3072 + 1536 + 1536 = 73216 B (2 blocks/CU, 17KB margin)
  __shared__ alignas(16) short tst[8][2048];      // 32 KB: per-wave 4KB stash (+atn alias)
  __shared__ alignas(16) short wbuf[4][4096];     // 32 KB: 4-slot chunk ring
  __shared__ short ckb3[768];                     // bf16 ck, all layers
  __shared__ float sadd3[768];                    // f32 cvo, all layers
  __shared__ short sg3[768];                      // bf16 LN gamma
  __shared__ short sb3[768];                      // bf16 LN beta

  #define LKW  asm volatile("s_waitcnt lgkmcnt(0)" ::: "memory")
  #define VMW0 asm volatile("s_waitcnt vmcnt(0)" ::: "memory")
  #define VMW1 asm volatile("s_waitcnt vmcnt(1)" ::: "memory")
  #define VMW2 asm volatile("s_waitcnt vmcnt(2)" ::: "memory")
  #define BAR  __builtin_amdgcn_s_barrier()

  // chunk n (0..95): layer n>>5, gemm (n>>4)&1, c = n&15 -> (h = c>>3, kk = c&7)
  auto STAGE = [&](int n){
    int cc = n & 15;
    const short* W = (((n >> 4) & 1) ? Wvo : Wqk) + (n >> 5)*65536;
    const short* src = W + ((((cc & 7)*16 + (cc >> 3)*8) << 9) + tid*8);
    gload16(src, &wbuf[n & 3][tid*8]);
  };

  // ===== input projection: h = rf@Wi + bi (B frag-packed direct-global) =====
  float* hst  = (float*)&tst[0][0];   // [16][264] f32 (16.9 KB inside tst)
  float* embs = hst + 16*264;
  float* bis  = embs + 2048;
  if (tid < 256) bis[tid] = bi[tid];
  for (int i = tid; i < 2048; i += 512) embs[i] = emb[i];
  f32x4 hacc[2] = {};
  #pragma unroll
  for (int kk = 0; kk < 16; kk++){
    const float* ap = rf + (size_t)(b0 + (lane & 15)) * 512 + kk*32 + dsub;
    float4 a0 = *(const float4*)ap, a1 = *(const float4*)(ap + 4);
    float af[8] = {a0.x,a0.y,a0.z,a0.w,a1.x,a1.y,a1.z,a1.w};
    bf16x8 av = pk8(af);
    #pragma unroll
    for (int nj = 0; nj < 2; nj++){
      bf16x8 bv = *(const bf16x8*)(WiT + (size_t)(kk*16 + w*2 + nj)*512 + lane*8);
      hacc[nj] = __builtin_amdgcn_mfma_f32_16x16x32_bf16(av, bv, hacc[nj], 0, 0, 0);
    }
  }
  for (int i = tid; i < 768; i += 512){
    ckb3[i]  = (short)f2bf(ckv[i]);
    sadd3[i] = cvov[i];
    sg3[i]   = (short)f2bf(lng[i]);
    sb3[i]   = (short)f2bf(lnb[i]);
  }
  __syncthreads();   // bis/embs published
  #pragma unroll
  for (int nj = 0; nj < 2; nj++)
    #pragma unroll
    for (int jj = 0; jj < 4; jj++){
      int m = (lane >> 4)*4 + jj, col = w*32 + nj*16 + (lane & 15);
      hst[m*264 + col] = hacc[nj][jj] + bis[col];
    }
  __syncthreads();   // hst published
  bf16x8 xf[8];
  {
    int r15 = lane & 15;
    int bt = w*2 + (r15 >> 3), ct = r15 & 7;
    #pragma unroll
    for (int c = 0; c < 8; c++){
      float v8[8];
      #pragma unroll
      for (int e = 0; e < 8; e++){
        int d = dsub + 32*c + e;
        v8[e] = hst[bt*264 + d] + embs[ct*256 + d];
      }
      xf[c] = pk8(v8);
    }
  }
  VMW0; __syncthreads();   // drain all VMEM before the ring stream
  STAGE(0); STAGE(1); STAGE(2);

  const unsigned long long MASK64 = 0x02191D69752B857EULL;

  // ===== layers (chunk stream n = l*32 + g*16 + c, prefetch distance 3) =====
  #pragma unroll 1
  for (int l = 0; l < 3; ++l){
    const short* ckb  = ckb3  + l*256;
    const float* sadd = sadd3 + l*256;
    const short* sg   = sg3   + l*256;
    const short* sb   = sb3   + l*256;
    const bool lgl = (l == 2);

    // ---- GEMM1: T = X @ Wqk ----
    f32x4 sacc = {0.f, 0.f, 0.f, 0.f};
    #pragma unroll
    for (int h = 0; h < 2; h++){
      f32x4 acc[8] = {};
      #pragma unroll
      for (int kk = 0; kk < 8; kk++){
        const int n = l*32 + h*8 + kk;
        VMW2; BAR;
        STAGE(n + 3);
        const short* P = &wbuf[n & 3][0];
        #pragma unroll
        for (int nj = 0; nj < 8; nj++){
          bf16x8 bv = *(const bf16x8*)&P[nj*512 + lane*8];
          acc[nj] = __builtin_amdgcn_mfma_f32_16x16x32_bf16(xf[kk], bv, acc[nj], 0, 0, 0);
        }
      }
      // T-half -> per-wave stash (bf16, swizzled), then score MFMA
      #pragma unroll
      for (int nj = 0; nj < 8; nj++)
        #pragma unroll
        for (int jj = 0; jj < 4; jj++){
          int i_ = (lane >> 4)*4 + jj, nl = nj*16 + (lane & 15);
          tst[w][(nl >> 5)*512 + gsw(i_, (nl >> 3) & 3)*8 + (nl & 7)] = (short)f2bf(acc[nj][jj]);
        }
      LKW; __builtin_amdgcn_sched_barrier(0);
      #pragma unroll
      for (int cl = 0; cl < 4; cl++){
        bf16x8 tf = *(const bf16x8*)&tst[w][cl*512 + glane*8];
        sacc = __builtin_amdgcn_mfma_f32_16x16x32_bf16(tf, xf[h*4 + cl], sacc, 0, 0, 0);
      }
      LKW;   // stash reads drained before next-half overwrite
    }

    // ---- skv[m] = X[m].ck ----
    float skv = 0.f;
    #pragma unroll
    for (int c = 0; c < 8; c++){
      bf16x8 cv = *(const bf16x8*)&ckb[c*32 + dsub];
      #pragma unroll
      for (int e = 0; e < 8; e++) skv = fmaf(bfs(xf[c][e]), bfs(cv[e]), skv);
    }
    skv += __shfl_xor(skv, 16); skv += __shfl_xor(skv, 32);

    // ---- softmax (C-layout) -> atn aliased into tst[w][0..511] ----
    float* atnw = (float*)&tst[w][0];   // 256 floats (1 KB), tst dead here
    #pragma unroll
    for (int jj = 0; jj < 4; jj++){
      int i_ = (lane >> 4)*4 + jj, j_ = lane & 15;
      bool ok = (((i_ ^ j_) & 8) == 0) &&
                ((MASK64 >> (((i_ & 7) << 3) | (j_ & 7))) & 1ull);
      float sv = ok ? (sacc[jj] + skv) : -3.0e38f;
      float mx = sv;
      mx = fmaxf(mx, __shfl_xor(mx, 1));
      mx = fmaxf(mx, __shfl_xor(mx, 2));
      mx = fmaxf(mx, __shfl_xor(mx, 4));
      float e = ok ? __expf(sv - mx) : 0.f;
      float sum = e;
      sum += __shfl_xor(sum, 1); sum += __shfl_xor(sum, 2); sum += __shfl_xor(sum, 4);
      atnw[i_*16 + j_] = e / sum;
    }
    LKW;

    // ---- PV: yfrag (A-layout) via shfl from xf ----
    bf16x8 yfrag[8];
    {
      float4 A0 = *(const float4*)&atnw[(lane & 15)*16 + (lane & 8)];
      float4 A1 = *(const float4*)&atnw[(lane & 15)*16 + (lane & 8) + 4];
      float am[8] = {A0.x, A0.y, A0.z, A0.w, A1.x, A1.y, A1.z, A1.w};
      #pragma unroll
      for (int c = 0; c < 8; c++){
        float a8[8] = {0,0,0,0,0,0,0,0};
        #pragma unroll
        for (int mi = 0; mi < 8; mi++){
          bf16x8 xs = shfl8(xf[c], (lane & 48) | (lane & 8) | mi);
          #pragma unroll
          for (int e = 0; e < 8; e++) a8[e] = fmaf(am[mi], bfs(xs[e]), a8[e]);
        }
        yfrag[c] = pk8(a8);
      }
    }
    LKW;   // atn reads drained before GEMM2 exchange overwrites tst[w]

    // ---- GEMM2: out = y @ Wvo; bf16 exchange epilogue per half ----
    float rs = 0.f, rq = 0.f;
    #pragma unroll
    for (int h = 0; h < 2; h++){
      f32x4 acc[8] = {};
      #pragma unroll
      for (int kk = 0; kk < 8; kk++){
        const int c = h*8 + kk;
        const int n = l*32 + 16 + c;
        if (lgl && c == 14){ VMW1; } else if (lgl && c == 15){ VMW0; } else { VMW2; }
        BAR;
        if (!(lgl && c >= 13)) STAGE(n + 3);
        const short* P = &wbuf[n & 3][0];
        #pragma unroll
        for (int nj = 0; nj < 8; nj++){
          bf16x8 bv = *(const bf16x8*)&P[nj*512 + lane*8];
          acc[nj] = __builtin_amdgcn_mfma_f32_16x16x32_bf16(yfrag[kk], bv, acc[nj], 0, 0, 0);
        }
      }
      #pragma unroll
      for (int nj = 0; nj < 8; nj++)
        #pragma unroll
        for (int jj = 0; jj < 4; jj++){
          int i_ = (lane >> 4)*4 + jj;
          int dq = nj*16 + (lane & 15);
          tst[w][(dq >> 5)*512 + gsw(i_, (dq >> 3) & 3)*8 + (dq & 7)] = (short)f2bf(acc[nj][jj]);
        }
      LKW; __builtin_amdgcn_sched_barrier(0);
      #pragma unroll
      for (int lc = 0; lc < 4; lc++){
        int c = h*4 + lc;
        float v8[8];
        #pragma unroll
        for (int e = 0; e < 8; e++){
          int d = 32*c + dsub + e;
          float t = bfs(tst[w][lc*512 + glane*8 + e]) + sadd[d] + bfs(xf[c][e]);
          rs += t; rq = fmaf(t, t, rq);
          v8[e] = t;
        }
        xf[c] = pk8(v8);
      }
      LKW;
    }
    // ---- per-row LN stats + apply ----
    rs += __shfl_xor(rs, 16); rs += __shfl_xor(rs, 32);
    rq += __shfl_xor(rq, 16); rq += __shfl_xor(rq, 32);
    float mn = rs * (1.f/256.f);
    float var = rq * (1.f/256.f) - mn*mn;
    float rr = rsqrtf(fmaxf(var, 0.f) + 1e-5f);
    #pragma unroll
    for (int c = 0; c < 8; c++){
      float v8[8];
      #pragma unroll
      for (int e = 0; e < 8; e++){
        int d = 32*c + dsub + e;
        v8[e] = (bfs(xf[c][e]) - mn) * rr * bfs(sg[d]) + bfs(sb[d]);
      }
      xf[c] = pk8(v8);
    }
  } // layers

  // ===== head: GDP-reduce -> Astage -> GEMM vs frag-packed WpT -> LN -> GELU =====
  __syncthreads();   // tst becomes cross-wave Astage
  short* Ast = &tst[0][0];   // [16][264] bf16 (8.4 KB, spans tst[0..2])
  {
    int c7 = lane & 7;
    float g = (c7 == 0) ? 0.4f : (c7 == 1) ? 0.15f : (c7 == 2) ? 0.12f :
              (c7 == 3) ? 0.1f : (c7 == 4) ? 0.08f : (c7 == 5) ? 0.08f :
              (c7 == 6) ? 0.05f : 0.02f;
    #pragma unroll
    for (int c = 0; c < 8; c++){
      float v8[8];
      #pragma unroll
      for (int e = 0; e < 8; e++){
        float v = g * bfs(xf[c][e]);
        v += __shfl_xor(v, 1); v += __shfl_xor(v, 2); v += __shfl_xor(v, 4);
        v8[e] = v;
      }
      if ((lane & 7) == 0){
        int bt = w*2 + ((lane >> 3) & 1);
        *(bf16x8*)&Ast[bt*264 + dsub + 32*c] = pk8(v8);
      }
    }
  }
  __syncthreads();
  float* redS  = (float*)&tst[6][0];     // head scratch in dead tst[6] (1.2 KB)
  float* redQ  = redS + 128;
  float* s_mn  = redQ + 128;
  float* s_rs  = s_mn + 16;
  f32x4 ha[2] = {};
  #pragma unroll
  for (int kk = 0; kk < 8; kk++){
    bf16x8 av = *(const bf16x8*)&Ast[(lane & 15)*264 + kk*32 + dsub];
    #pragma unroll
    for (int nj = 0; nj < 2; nj++){
      bf16x8 bv = *(const bf16x8*)(WpT + (size_t)(kk*16 + w*2 + nj)*512 + lane*8);
      ha[nj] = __builtin_amdgcn_mfma_f32_16x16x32_bf16(av, bv, ha[nj], 0, 0, 0);
    }
  }
  #pragma unroll
  for (int jj = 0; jj < 4; jj++){
    float s = 0.f, q = 0.f;
    #pragma unroll
    for (int nj = 0; nj < 2; nj++){
      int cx = w*32 + nj*16 + (lane & 15);
      float t = ha[nj][jj] + bpv[cx];
      ha[nj][jj] = t;
      s += t; q = fmaf(t, t, q);
    }
    s += __shfl_xor(s, 1); q += __shfl_xor(q, 1);
    s += __shfl_xor(s, 2); q += __shfl_xor(q, 2);
    s += __shfl_xor(s, 4); q += __shfl_xor(q, 4);
    s += __shfl_xor(s, 8); q += __shfl_xor(q, 8);
    if ((lane & 15) == 0){
      int rl = (lane >> 4)*4 + jj;
      redS[w*16 + rl] = s; redQ[w*16 + rl] = q;
    }
  }
  __syncthreads();
  if (tid < 16){
    float sm = 0.f, sq = 0.f;
    #pragma unroll
    for (int w2 = 0; w2 < 8; w2++){ sm += redS[w2*16 + tid]; sq += redQ[w2*16 + tid]; }
    float mn = sm * (1.f/256.f);
    float var = sq * (1.f/256.f) - mn*mn;
    s_mn[tid] = mn;
    s_rs[tid] = rsqrtf(fmaxf(var, 0.f) + 1e-5f);
  }
  __syncthreads();
  #pragma unroll
  for (int jj = 0; jj < 4; jj++){
    int rl = (lane >> 4)*4 + jj;
    float mn = s_mn[rl], rstd = s_rs[rl];
    #pragma unroll
    for (int nj = 0; nj < 2; nj++){
      int cx = w*32 + nj*16 + (lane & 15);
      float y = (ha[nj][jj] - mn) * rstd * lpg[cx] + lpb[cx];
      outp[(size_t)(b0 + rl)*256 + cx] = 0.5f * y * (1.0f + erff(y * 0.70710678118654752f));
    }
  }
  #undef LKW
  #undef VMW0
  #undef VMW1
  #undef VMW2
  #undef BAR
}

extern "C" void kernel_launch(void* const* d_in, const int* in_sizes, int n_in,
                              void* d_out, int out_size, void* d_ws, size_t ws_size,
                              hipStream_t stream){
  (void)in_sizes; (void)n_in; (void)out_size; (void)ws_size;
  const float* rf  = (const float*)d_in[0];
  const float* Wi  = (const float*)d_in[1];
  const float* bi  = (const float*)d_in[2];
  const float* emb = (const float*)d_in[3];
  const float* Wq  = (const float*)d_in[4];
  const float* bq  = (const float*)d_in[5];
  const float* Wk  = (const float*)d_in[6];
  const float* bk  = (const float*)d_in[7];
  const float* Wv  = (const float*)d_in[8];
  const float* bv  = (const float*)d_in[9];
  const float* Wo  = (const float*)d_in[10];
  const float* bo  = (const float*)d_in[11];
  const float* lng = (const float*)d_in[12];
  const float* lnb = (const float*)d_in[13];
  const float* Wp  = (const float*)d_in[14];
  const float* bp  = (const float*)d_in[15];
  const float* lpg = (const float*)d_in[16];
  const float* lpb = (const float*)d_in[17];
  (void)bk;

  char* ws = (char*)d_ws;
  short* Wqb  = (short*)(ws);                      // [3][256][1024] bf16
  short* Wkb  = (short*)(ws + 1572864ull);
  short* Wvb  = (short*)(ws + 3145728ull);
  short* WoTb = (short*)(ws + 4718592ull);         // [3][256][1024] row-major
  short* WqkP = (short*)(ws + 6291456ull);         // [3][8][16][512] packed (scaled 1/16)
  short* WvoP = (short*)(ws + 6684672ull);         // [3][8][16][512] packed
  short* WiTP = (short*)(ws + 7077888ull);         // [16][16][512] packed
  short* WpTP = (short*)(ws + 7340032ull);         // [8][16][512] packed
  float* ckv  = (float*)(ws + 7471104ull);
  float* cvov = (float*)(ws + 7474176ull);

  { P1P p;
    p.csrc[0]=Wq; p.cdst[0]=Wqb;
    p.csrc[1]=Wk; p.cdst[1]=Wkb;
    p.csrc[2]=Wv; p.cdst[2]=Wvb;
    p.tsrc[0]=Wi;        p.tdst[0]=WiTP;          p.trows[0]=512;  p.tcols[0]=256; p.tpack[0]=1;
    p.tsrc[1]=Wo;        p.tdst[1]=WoTb;          p.trows[1]=1024; p.tcols[1]=256; p.tpack[1]=0;
    p.tsrc[2]=Wo+262144; p.tdst[2]=WoTb+262144;   p.trows[2]=1024; p.tcols[2]=256; p.tpack[2]=0;
    p.tsrc[3]=Wo+524288; p.tdst[3]=WoTb+524288;   p.trows[3]=1024; p.tcols[3]=256; p.tpack[3]=0;
    p.tsrc[4]=Wp;        p.tdst[4]=WpTP;          p.trows[4]=256;  p.tcols[4]=256; p.tpack[4]=1;
    p.toff[0]=0; p.toff[1]=32; p.toff[2]=96; p.toff[3]=160; p.toff[4]=224; p.toff[5]=240;
    k_prep1<<<dim3(1392), dim3(256), 0, stream>>>(p); }

  { P2P p;
    for (int l = 0; l < 3; l++){
      p.d[l]   = GD2{ Wkb  + l*262144, Wqb + l*262144, WqkP + l*65536, 0.0625f };
      p.d[3+l] = GD2{ WoTb + l*262144, Wvb + l*262144, WvoP + l*65536, 1.0f };
    }
    p.Wkb = Wkb; p.WoTb = WoTb;
    p.bq = bq; p.bv = bv; p.bo = bo;
    p.ck = ckv; p.cvo = cvov;
    k_prep2<<<dim3(102), dim3(256), 0, stream>>>(p); }

  k_net<<<dim3(512), dim3(512), 0, stream>>>(rf, WiTP, bi, emb, WqkP, WvoP,
      ckv, cvov, lng, lnb, WpTP, bp, lpg, lpb, (float*)d_out);
}